// Round 6
// baseline (23427.896 us; speedup 1.0000x reference)
//
#include <hip/hip_runtime.h>
#include <stdint.h>

typedef unsigned short u16;
typedef unsigned long long u64;
typedef __bf16 bf16x8 __attribute__((ext_vector_type(8)));
typedef float f32x4 __attribute__((ext_vector_type(4)));

#define S_LEN 288
#define T_LEN 144
#define HID   512
#define BATCH 2048
#define NBLK  256
#define THREADS 512
#define HBUF  ((size_t)BATCH * HID)

// LDS arena (u16 elems): two staged A tiles + h scratch + 1KB touch dump
#define ATILE  32768
#define SCROFF (2*ATILE)
#define DUMPOFF (2*ATILE + 64*72)
#define ARENA_ELEMS (2*ATILE + 64*72 + 512)   // 141312 B -> 1 block/CU -> 32 blocks/XCD

#define MFMA16(a,b,c) __builtin_amdgcn_mfma_f32_16x16x32_bf16((a),(b),(c),0,0,0)

__device__ __forceinline__ u16 f2bf(float f){
  unsigned u = __builtin_bit_cast(unsigned, f);
  u = u + 0x7fffu + ((u >> 16) & 1u);
  return (u16)(u >> 16);
}
__device__ __forceinline__ float sigf(float x){ return 1.0f/(1.0f + __expf(-x)); }
__device__ __forceinline__ float tanh_f(float x){ return 1.0f - 2.0f/(1.0f + __expf(2.0f*x)); }

// agent-scope — ONLY for barrier counters / roster / preds (tiny, cross-L2)
__device__ __forceinline__ float aloadf(const float* p){
  return __hip_atomic_load(p, __ATOMIC_RELAXED, __HIP_MEMORY_SCOPE_AGENT);
}
__device__ __forceinline__ void astoref(float* p, float v){
  __hip_atomic_store(p, v, __ATOMIC_RELAXED, __HIP_MEMORY_SCOPE_AGENT);
}

// async global->LDS, 16B/lane, aux=1 (sc0: bypass L1, read XCD-local L2)
__device__ __forceinline__ void glds16(const u16* g, u16* l){
  __builtin_amdgcn_global_load_lds(
      (const __attribute__((address_space(1))) void*)g,
      (__attribute__((address_space(3))) void*)l, 16, 0, 1);
}

// LDS-only barrier: orders ds_write/ds_read across waves WITHOUT draining vmcnt —
// lets touch-prefetch loads stay in flight through the epilogue (drained at gbar).
__device__ __forceinline__ void bar_lds(){
  asm volatile("s_waitcnt lgkmcnt(0)" ::: "memory");
  __builtin_amdgcn_s_barrier();
}

struct Params {
  const float* xT;     // transposed input [S][B]
  const u16 *We0, *We1i, *We1h, *Wd0, *Wd1i, *Wd1h;
  const float *be0, *be1, *bd0, *bd1, *wxe, *wxd, *fcW, *fcbp;
  u16 *h0buf, *h1buf;
  float* preds;
  unsigned* gcnt;
  unsigned* roster;
  float* out;
};

// ---------------- prep kernels ----------------
// orig row = gate*512 + hu  ->  new row = (hu>>3)*32 + gate*8 + (hu&7)
__global__ void k_reorder_w(const float* __restrict__ src, u16* __restrict__ dst){
  int idx  = blockIdx.x * 256 + threadIdx.x;
  int k    = idx & (HID-1);
  int orig = idx >> 9;
  int gate = orig >> 9, hu = orig & (HID-1);
  int nr   = ((hu >> 3) << 5) + (gate << 3) + (hu & 7);
  dst[(size_t)nr * HID + k] = f2bf(src[idx]);
}

__global__ void k_prep_small(const float* __restrict__ bih, const float* __restrict__ bhh,
                             float* __restrict__ bdst,
                             const float* __restrict__ wcol, float* __restrict__ wdst){
  int orig = blockIdx.x * 256 + threadIdx.x;
  int gate = orig >> 9, hu = orig & (HID-1);
  int nr   = ((hu >> 3) << 5) + (gate << 3) + (hu & 7);
  bdst[nr] = bih[orig] + bhh[orig];
  if (wcol) wdst[nr] = wcol[orig];
}

// x[B][S] -> xT[S][B]: coalesced per-phase x reads, one-time
__global__ void k_xpose(const float* __restrict__ x, float* __restrict__ xT){
  int idx = blockIdx.x * 256 + threadIdx.x;
  int b = idx / S_LEN, s = idx - b*S_LEN;
  xT[(size_t)s * BATCH + b] = x[idx];
}

// ---------------- per-XCD barrier (32 blocks), RELAXED ----------------
// gbar's __syncthreads drains vmcnt(0): h stores (and touches) are in L2 before
// tid0 bumps the counter -> peers that observe the count observe h.
__device__ __forceinline__ void gbar(unsigned* cnt, unsigned& epoch){
  __syncthreads();
  ++epoch;
  if (threadIdx.x == 0){
    __hip_atomic_fetch_add(cnt, 1u, __ATOMIC_RELAXED, __HIP_MEMORY_SCOPE_AGENT);
    const unsigned tgt = epoch * 32u;
    while (__hip_atomic_load(cnt, __ATOMIC_RELAXED, __HIP_MEMORY_SCOPE_AGENT) < tgt)
      __builtin_amdgcn_s_sleep(1);
  }
  __syncthreads();
}

// ---------------- A-tile staging (sc0 -> XCD L2), source-swizzled ----------------
__device__ __forceinline__ void stage_tile(const u16* __restrict__ Ag, u16* lA,
                                           int wave, int lane){
  const int r_in = lane >> 2, qq = lane & 3;
  const int qg = qq ^ ((r_in >> 2) & 3);
  #pragma unroll
  for (int j = 0; j < 8; ++j){
    const int idx = wave*8 + j;
    const int c = idx >> 2, rq = idx & 3;
    const u16* g = Ag + (size_t)(rq*16 + r_in)*HID + c*32 + qg*8;
    glds16(g, lA + c*2048 + rq*512);
  }
}

// ---------------- touch-prefetch: refresh/fill a weight stream's n_sub slice ----
// Each block touches its quarter of the slice: 64 rows x 1KB via 8 glds16/thread
// into the dump buffer (no VGPR results, no waits). Fills L2 during epilogue.
__device__ __forceinline__ void touch_stream(const u16* __restrict__ W, u16* dump,
                                             int n_sub, int m_sub, int wave, int lane){
  const int row = n_sub*256 + m_sub*64 + wave*8 + (lane >> 3);
  const u16* base = W + (size_t)row*HID + (lane & 7)*8;
  #pragma unroll
  for (int j = 0; j < 8; ++j)
    glds16(base + j*64, dump);
}

// K-chunk permutation: cc = (cb + cs*i) & 15, cb = dir?15:0, cs = dir?-1:+1.
// PURE zigzag across phases (LRU-thrash fix; R5: FETCH -44%).

// ---------------- fused encoder K-loop: 2 A-tiles x 3 B-streams, depth-4 --------
__device__ __forceinline__ void gemm_enc(
    const u16* lA0, const u16* lA1,
    const u16* __restrict__ B0, const u16* __restrict__ B1, const u16* __restrict__ B2,
    f32x4 (&acc0)[4][2], f32x4 (&acc1)[4][2],
    const int (&aloff)[4], const int (&boff)[2], int cb, int cs)
{
  int4 q0[4][2], q1[4][2], q2[4][2];
  #pragma unroll
  for (int st = 0; st < 4; ++st){
    const int cc = (cb + cs*st) & 15;
    #pragma unroll
    for (int nf = 0; nf < 2; ++nf){
      q0[st][nf] = *(const int4*)(B0 + boff[nf] + cc*32);
      q1[st][nf] = *(const int4*)(B1 + boff[nf] + cc*32);
      q2[st][nf] = *(const int4*)(B2 + boff[nf] + cc*32);
    }
  }
  __syncthreads();   // glds16 staging + primes drained
  #pragma unroll
  for (int i = 0; i < 16; ++i){
    const int cc = (cb + cs*i) & 15;
    bf16x8 a0[4], a1[4];
    #pragma unroll
    for (int mf = 0; mf < 4; ++mf){
      a0[mf] = *(const bf16x8*)&lA0[cc*2048 + aloff[mf]];
      a1[mf] = *(const bf16x8*)&lA1[cc*2048 + aloff[mf]];
    }
    const int st = i & 3;
    #pragma unroll
    for (int mf = 0; mf < 4; ++mf)
      #pragma unroll
      for (int nf = 0; nf < 2; ++nf){
        acc0[mf][nf] = MFMA16(a0[mf], __builtin_bit_cast(bf16x8, q0[st][nf]), acc0[mf][nf]);
        acc1[mf][nf] = MFMA16(a0[mf], __builtin_bit_cast(bf16x8, q1[st][nf]), acc1[mf][nf]);
        acc1[mf][nf] = MFMA16(a1[mf], __builtin_bit_cast(bf16x8, q2[st][nf]), acc1[mf][nf]);
      }
    if (i < 12){
      const int cn = (cb + cs*(i+4)) & 15;
      #pragma unroll
      for (int nf = 0; nf < 2; ++nf){
        q0[st][nf] = *(const int4*)(B0 + boff[nf] + cn*32);
        q1[st][nf] = *(const int4*)(B1 + boff[nf] + cn*32);
        q2[st][nf] = *(const int4*)(B2 + boff[nf] + cn*32);
      }
    }
  }
}

// ---------------- decoder phase A: 1 A-tile x 1 B-stream, depth-8 ----------------
__device__ __forceinline__ void gemm_dec1(
    const u16* lA0, const u16* __restrict__ B0,
    f32x4 (&acc)[4][2], const int (&aloff)[4], const int (&boff)[2], int cb, int cs)
{
  int4 q[8][2];
  #pragma unroll
  for (int st = 0; st < 8; ++st){
    const int cc = (cb + cs*st) & 15;
    #pragma unroll
    for (int nf = 0; nf < 2; ++nf)
      q[st][nf] = *(const int4*)(B0 + boff[nf] + cc*32);
  }
  __syncthreads();
  #pragma unroll
  for (int i = 0; i < 16; ++i){
    const int cc = (cb + cs*i) & 15;
    bf16x8 a0[4];
    #pragma unroll
    for (int mf = 0; mf < 4; ++mf)
      a0[mf] = *(const bf16x8*)&lA0[cc*2048 + aloff[mf]];
    const int st = i & 7;
    #pragma unroll
    for (int mf = 0; mf < 4; ++mf)
      #pragma unroll
      for (int nf = 0; nf < 2; ++nf)
        acc[mf][nf] = MFMA16(a0[mf], __builtin_bit_cast(bf16x8, q[st][nf]), acc[mf][nf]);
    if (i < 8){
      const int cn = (cb + cs*(i+8)) & 15;
      #pragma unroll
      for (int nf = 0; nf < 2; ++nf)
        q[st][nf] = *(const int4*)(B0 + boff[nf] + cn*32);
    }
  }
}

// ---------------- decoder phase B: 2 A-tiles x 2 B-streams, depth-5 --------------
__device__ __forceinline__ void gemm_dec2(
    const u16* lA0, const u16* lA1,
    const u16* __restrict__ B1, const u16* __restrict__ B2,
    f32x4 (&acc)[4][2], const int (&aloff)[4], const int (&boff)[2], int cb, int cs)
{
  int4 q1[5][2], q2[5][2];
  #pragma unroll
  for (int st = 0; st < 5; ++st){
    const int cc = (cb + cs*st) & 15;
    #pragma unroll
    for (int nf = 0; nf < 2; ++nf){
      q1[st][nf] = *(const int4*)(B1 + boff[nf] + cc*32);
      q2[st][nf] = *(const int4*)(B2 + boff[nf] + cc*32);
    }
  }
  __syncthreads();
  #pragma unroll
  for (int i = 0; i < 16; ++i){
    const int cc = (cb + cs*i) & 15;
    bf16x8 a0[4], a1[4];
    #pragma unroll
    for (int mf = 0; mf < 4; ++mf){
      a0[mf] = *(const bf16x8*)&lA0[cc*2048 + aloff[mf]];
      a1[mf] = *(const bf16x8*)&lA1[cc*2048 + aloff[mf]];
    }
    const int st = i % 5;
    #pragma unroll
    for (int mf = 0; mf < 4; ++mf)
      #pragma unroll
      for (int nf = 0; nf < 2; ++nf){
        acc[mf][nf] = MFMA16(a0[mf], __builtin_bit_cast(bf16x8, q1[st][nf]), acc[mf][nf]);
        acc[mf][nf] = MFMA16(a1[mf], __builtin_bit_cast(bf16x8, q2[st][nf]), acc[mf][nf]);
      }
    if (i < 11){
      const int cn = (cb + cs*(i+5)) & 15;
      #pragma unroll
      for (int nf = 0; nf < 2; ++nf){
        q1[st][nf] = *(const int4*)(B1 + boff[nf] + cn*32);
        q2[st][nf] = *(const int4*)(B2 + boff[nf] + cn*32);
      }
    }
  }
}

// ---------------- LSTM cell epilogue (proven gate mapping) ----------------
template<bool X0, bool PRED>
__device__ __forceinline__ void cell_epi(
    f32x4 (&acc)[4][2], float* cst, const float* bv, const float* wxv,
    const float* xin, u16* scr,
    int wave, int quad, int l15, int m0,
    float fcWv, float* predrow)
{
  const int hilane = l15 >> 3, hu7 = l15 & 7;
  #pragma unroll
  for (int mf = 0; mf < 4; ++mf){
    #pragma unroll
    for (int r = 0; r < 4; ++r){
      const float a0 = acc[mf][0][r], a1 = acc[mf][1][r];
      const float p0 = __shfl_xor(a0, 8), p1 = __shfl_xor(a1, 8);
      float gi = (hilane ? p0 : a0) + bv[0];
      float gf = (hilane ? a0 : p0) + bv[1];
      float gg = (hilane ? p1 : a1) + bv[2];
      float go = (hilane ? a1 : p1) + bv[3];
      if (X0){
        const float xt = xin[mf*4 + r];
        gi += xt*wxv[0]; gf += xt*wxv[1]; gg += xt*wxv[2]; go += xt*wxv[3];
      }
      const float c = sigf(gf)*cst[mf*4+r] + sigf(gi)*tanh_f(gg);
      cst[mf*4+r] = c;
      const float h = sigf(go)*tanh_f(c);
      if (!hilane) scr[(mf*16 + quad*4 + r)*72 + wave*8 + hu7] = f2bf(h);
      if (PRED){
        float v = hilane ? 0.f : h*fcWv;
        v += __shfl_xor(v, 1); v += __shfl_xor(v, 2);
        v += __shfl_xor(v, 4); v += __shfl_xor(v, 8);
        if (l15 == 0) atomicAdd(&predrow[m0 + mf*16 + quad*4 + r], v);
      }
    }
  }
}

// drain scratch (64 rows x 64 cols, pitch 72) -> global h (plain stores -> XCD L2)
// lgkm-only barriers: scr handoff needs LDS ordering only; vmcnt (h stores +
// touch loads) drains once at gbar. Read->store dependency forces ds_read
// completion before store issue, so barrier 2 safely guards scr reuse.
__device__ __forceinline__ void drain_h(const u16* scr, u16* hdst, int m0, int col0, int tid){
  bar_lds();
  const int row = tid >> 3, q = tid & 7;
  const int4 v = *(const int4*)(scr + row*72 + q*8);
  *(int4*)(hdst + (size_t)(m0+row)*HID + col0 + q*8) = v;
  bar_lds();
}

// ---------------- persistent main kernel ----------------
__global__ __launch_bounds__(THREADS, 1) void lstm_main(Params P){
  const int tid = threadIdx.x;
  const int wave = tid >> 6, lane = tid & 63;
  const int l15 = lane & 15, quad = lane >> 4;
  const int hu7 = l15 & 7;

  __shared__ u16 arena[ARENA_ELEMS];   // 141.3 KB -> 1 block/CU -> 32 blocks/XCD
  __shared__ unsigned sslot;
  u16* lA0 = arena;
  u16* lA1 = arena + ATILE;
  u16* scr = arena + SCROFF;
  u16* dump = arena + DUMPOFF;

  // ---- dynamic XCD roster ----
  unsigned xcd;
  asm volatile("s_getreg_b32 %0, hwreg(HW_REG_XCC_ID)" : "=s"(xcd));
  if (tid == 0)
    sslot = __hip_atomic_fetch_add(&P.roster[xcd*32], 1u, __ATOMIC_RELAXED,
                                   __HIP_MEMORY_SCOPE_AGENT);
  __syncthreads();
  const int slot  = (int)(sslot & 31u);
  const int m_sub = slot & 3;
  const int n_sub = slot >> 2;
  const int m0   = (int)xcd*256 + m_sub*64;
  const int col0 = n_sub*64;
  const int hu   = col0 + wave*8 + hu7;

  unsigned* cnt = P.gcnt + xcd*32;

  // fragment offsets: read slot = quad ^ swz(l15) (matches staging source permute)
  const int swz = (l15 >> 2) & 3;
  int aloff[4], boff[2];
  #pragma unroll
  for (int mf = 0; mf < 4; ++mf)
    aloff[mf] = (mf*16 + l15)*32 + ((quad ^ swz) << 3);
  #pragma unroll
  for (int nf = 0; nf < 2; ++nf)
    boff[nf] = (n_sub*256 + wave*32 + nf*16 + l15)*HID + quad*8;

  float c0s[16], c1s[16];
  #pragma unroll
  for (int i = 0; i < 16; ++i){ c0s[i] = 0.f; c1s[i] = 0.f; }

  float be0v[4], be1v[4], bd0v[4], bd1v[4], wxev[4], wxdv[4];
  #pragma unroll
  for (int g = 0; g < 4; ++g){
    const int col = n_sub*256 + wave*32 + g*8 + hu7;
    be0v[g] = P.be0[col]; be1v[g] = P.be1[col];
    bd0v[g] = P.bd0[col]; bd1v[g] = P.bd1[col];
    wxev[g] = P.wxe[col]; wxdv[g] = P.wxd[col];
  }
  const float fcWv = P.fcW[hu];
  const float fcb  = P.fcbp[0];

  const size_t mb = (size_t)m0 * HID;
  u16* h0b[2] = { P.h0buf, P.h0buf + HBUF };
  u16* h1b[2] = { P.h1buf, P.h1buf + HBUF };

  unsigned epoch = 0;
  gbar(cnt, epoch);   // roster settled

  // ===== encoder: phase p runs layer0(t=p) and layer1(t=p-1) =====
  for (int p = 0; p <= S_LEN; ++p){
    stage_tile(h0b[p & 1] + mb,     lA0, wave, lane);
    stage_tile(h1b[(p+1) & 1] + mb, lA1, wave, lane);

    // pure zigzag K-scan: reverse direction each phase (L2 LRU-thrash fix)
    const int dir = p & 1;
    const int cb  = dir ? 15 : 0;
    const int cs  = dir ? -1 : 1;

    float xin[16];
    if (p < S_LEN){
      #pragma unroll
      for (int mf = 0; mf < 4; ++mf)
        #pragma unroll
        for (int r = 0; r < 4; ++r)
          xin[mf*4+r] = P.xT[(size_t)p*BATCH + m0 + mf*16 + quad*4 + r];
    }

    f32x4 acc0[4][2], acc1[4][2];
    #pragma unroll
    for (int i = 0; i < 4; ++i)
      #pragma unroll
      for (int j = 0; j < 2; ++j){ acc0[i][j] = f32x4{0.f,0.f,0.f,0.f}; acc1[i][j] = f32x4{0.f,0.f,0.f,0.f}; }

    gemm_enc(lA0, lA1, P.We0, P.We1i, P.We1h, acc0, acc1, aloff, boff, cb, cs);

    // touch-prefetch next phase's weights during the epilogue (fills L2 async)
    if (p < S_LEN - 1){
      touch_stream(P.We0,  dump, n_sub, m_sub, wave, lane);
      touch_stream(P.We1i, dump, n_sub, m_sub, wave, lane);
      touch_stream(P.We1h, dump, n_sub, m_sub, wave, lane);
    } else {
      touch_stream(P.Wd0,  dump, n_sub, m_sub, wave, lane);
      touch_stream(P.Wd1i, dump, n_sub, m_sub, wave, lane);
      touch_stream(P.Wd1h, dump, n_sub, m_sub, wave, lane);
    }

    if (p < S_LEN){
      cell_epi<true,false>(acc0, c0s, be0v, wxev, xin, scr, wave, quad, l15, m0, 0.f, nullptr);
      drain_h(scr, h0b[(p+1) & 1], m0, col0, tid);
    }
    if (p >= 1){
      cell_epi<false,false>(acc1, c1s, be1v, nullptr, nullptr, scr, wave, quad, l15, m0, 0.f, nullptr);
      drain_h(scr, h1b[p & 1], m0, col0, tid);
    }
    gbar(cnt, epoch);
  }

  // ===== decoder: 2 phases per step (pred feedback) =====
  for (int t = 0; t < T_LEN; ++t){
    const int dir = t & 1;
    const int cb  = dir ? 15 : 0;
    const int cs  = dir ? -1 : 1;

    if (t > 0 && n_sub == 0 && tid < 64){
      const float pv = aloadf(&P.preds[((t+1) & 1)*BATCH + m0 + tid]);
      P.out[(size_t)(m0 + tid)*T_LEN + (t-1)] = pv + fcb;
    }
    { // phase A: dec layer0
      stage_tile(h0b[t & 1] + mb, lA0, wave, lane);
      float xin[16];
      #pragma unroll
      for (int mf = 0; mf < 4; ++mf)
        #pragma unroll
        for (int r = 0; r < 4; ++r){
          const int b = m0 + mf*16 + quad*4 + r;
          xin[mf*4+r] = (t == 0) ? P.xT[(size_t)(S_LEN-1)*BATCH + b]
                                 : (aloadf(&P.preds[((t+1) & 1)*BATCH + b]) + fcb);
        }
      f32x4 acc0[4][2];
      #pragma unroll
      for (int i = 0; i < 4; ++i)
        #pragma unroll
        for (int j = 0; j < 2; ++j) acc0[i][j] = f32x4{0.f,0.f,0.f,0.f};
      gemm_dec1(lA0, P.Wd0, acc0, aloff, boff, cb, cs);
      // prefetch phase B's streams during phase A epilogue
      touch_stream(P.Wd1i, dump, n_sub, m_sub, wave, lane);
      touch_stream(P.Wd1h, dump, n_sub, m_sub, wave, lane);
      cell_epi<true,false>(acc0, c0s, bd0v, wxdv, xin, scr, wave, quad, l15, m0, 0.f, nullptr);
      drain_h(scr, h0b[(t+1) & 1], m0, col0, tid);
    }
    gbar(cnt, epoch);
    // phase B: dec layer1 + pred reduce
    if (n_sub == 0 && tid < 64)
      astoref(&P.preds[((t+1) & 1)*BATCH + m0 + tid], 0.f);
    {
      stage_tile(h0b[(t+1) & 1] + mb, lA0, wave, lane);
      stage_tile(h1b[t & 1] + mb,     lA1, wave, lane);
      f32x4 acc1[4][2];
      #pragma unroll
      for (int i = 0; i < 4; ++i)
        #pragma unroll
        for (int j = 0; j < 2; ++j) acc1[i][j] = f32x4{0.f,0.f,0.f,0.f};
      gemm_dec2(lA0, lA1, P.Wd1i, P.Wd1h, acc1, aloff, boff, cb, cs);
      // prefetch next step's phase-A stream during phase B epilogue
      touch_stream(P.Wd0, dump, n_sub, m_sub, wave, lane);
      cell_epi<false,true>(acc1, c1s, bd1v, nullptr, nullptr, scr, wave, quad, l15, m0,
                           fcWv, P.preds + (t & 1)*BATCH);
      drain_h(scr, h1b[(t+1) & 1], m0, col0, tid);
    }
    gbar(cnt, epoch);
  }
  if (n_sub == 0 && tid < 64){
    const float pv = aloadf(&P.preds[((T_LEN-1) & 1)*BATCH + m0 + tid]);
    P.out[(size_t)(m0 + tid)*T_LEN + (T_LEN-1)] = pv + fcb;
  }
}

// ---------------- host launcher ----------------
extern "C" void kernel_launch(void* const* d_in, const int* in_sizes, int n_in,
                              void* d_out, int out_size, void* d_ws, size_t ws_size,
                              hipStream_t stream){
  const float* x     = (const float*)d_in[0];
  const float* eWih0 = (const float*)d_in[1];
  const float* eWhh0 = (const float*)d_in[2];
  const float* ebih0 = (const float*)d_in[3];
  const float* ebhh0 = (const float*)d_in[4];
  const float* eWih1 = (const float*)d_in[5];
  const float* eWhh1 = (const float*)d_in[6];
  const float* ebih1 = (const float*)d_in[7];
  const float* ebhh1 = (const float*)d_in[8];
  const float* dWih0 = (const float*)d_in[9];
  const float* dWhh0 = (const float*)d_in[10];
  const float* dbih0 = (const float*)d_in[11];
  const float* dbhh0 = (const float*)d_in[12];
  const float* dWih1 = (const float*)d_in[13];
  const float* dWhh1 = (const float*)d_in[14];
  const float* dbih1 = (const float*)d_in[15];
  const float* dbhh1 = (const float*)d_in[16];
  const float* fcW   = (const float*)d_in[17];
  const float* fcb   = (const float*)d_in[18];

  char* ws = (char*)d_ws;
  size_t off = 0;
  auto alloc = [&](size_t bytes)->char*{
    char* p = ws + off; off += (bytes + 255) & ~(size_t)255; return p;
  };
  u16* We0  = (u16*)alloc((size_t)2048*512*2);
  u16* We1i = (u16*)alloc((size_t)2048*512*2);
  u16* We1h = (u16*)alloc((size_t)2048*512*2);
  u16* Wd0  = (u16*)alloc((size_t)2048*512*2);
  u16* Wd1i = (u16*)alloc((size_t)2048*512*2);
  u16* Wd1h = (u16*)alloc((size_t)2048*512*2);
  char* zbase = ws + off;
  u16* h0buf = (u16*)alloc(2*HBUF*2);
  u16* h1buf = (u16*)alloc(2*HBUF*2);
  float* preds = (float*)alloc(2*BATCH*4);
  unsigned* gcnt   = (unsigned*)alloc(8*32*4);
  unsigned* roster = (unsigned*)alloc(8*32*4);
  size_t zbytes = (size_t)((ws + off) - zbase);
  float* be0 = (float*)alloc(2048*4);
  float* be1 = (float*)alloc(2048*4);
  float* bd0 = (float*)alloc(2048*4);
  float* bd1 = (float*)alloc(2048*4);
  float* wxe = (float*)alloc(2048*4);
  float* wxd = (float*)alloc(2048*4);
  float* xT  = (float*)alloc((size_t)BATCH*S_LEN*4);

  (void)hipMemsetAsync(zbase, 0, zbytes, stream);
  dim3 gw((2048*512)/256);
  k_reorder_w<<<gw,256,0,stream>>>(eWhh0, We0);
  k_reorder_w<<<gw,256,0,stream>>>(eWih1, We1i);
  k_reorder_w<<<gw,256,0,stream>>>(eWhh1, We1h);
  k_reorder_w<<<gw,256,0,stream>>>(dWhh0, Wd0);
  k_reorder_w<<<gw,256,0,stream>>>(dWih1, Wd1i);
  k_reorder_w<<<gw,256,0,stream>>>(dWhh1, Wd1h);
  k_prep_small<<<8,256,0,stream>>>(ebih0, ebhh0, be0, eWih0, wxe);
  k_prep_small<<<8,256,0,stream>>>(ebih1, ebhh1, be1, (const float*)nullptr, (float*)nullptr);
  k_prep_small<<<8,256,0,stream>>>(dbih0, dbhh0, bd0, dWih0, wxd);
  k_prep_small<<<8,256,0,stream>>>(dbih1, dbhh1, bd1, (const float*)nullptr, (float*)nullptr);
  k_xpose<<<dim3((BATCH*S_LEN)/256),256,0,stream>>>(x, xT);

  Params P{ xT, We0, We1i, We1h, Wd0, Wd1i, Wd1h,
            be0, be1, bd0, bd1, wxe, wxd, fcW, fcb,
            h0buf, h1buf, preds, gcnt, roster, (float*)d_out };
  lstm_main<<<dim3(NBLK), dim3(THREADS), 0, stream>>>(P);
}

// Round 7
// 15804.007 us; speedup vs baseline: 1.4824x; 1.4824x over previous
//
#include <hip/hip_runtime.h>
#include <stdint.h>

typedef unsigned short u16;
typedef unsigned long long u64;
typedef __bf16 bf16x8 __attribute__((ext_vector_type(8)));
typedef float f32x4 __attribute__((ext_vector_type(4)));

#define S_LEN 288
#define T_LEN 144
#define HID   512
#define BATCH 2048
#define NBLK  256
#define THREADS 512
#define HBUF  ((size_t)BATCH * HID)

// LDS arena (u16 elems): two staged A tiles (chunk-major, 64B rows) + h scratch
#define ATILE  32768
#define SCROFF (2*ATILE)
#define ARENA_ELEMS (2*ATILE + 64*72)    // 140288 B -> 1 block/CU -> 32 blocks/XCD

#define MFMA16(a,b,c) __builtin_amdgcn_mfma_f32_16x16x32_bf16((a),(b),(c),0,0,0)

__device__ __forceinline__ u16 f2bf(float f){
  unsigned u = __builtin_bit_cast(unsigned, f);
  u = u + 0x7fffu + ((u >> 16) & 1u);
  return (u16)(u >> 16);
}
__device__ __forceinline__ float sigf(float x){ return 1.0f/(1.0f + __expf(-x)); }
__device__ __forceinline__ float tanh_f(float x){ return 1.0f - 2.0f/(1.0f + __expf(2.0f*x)); }

// agent-scope — ONLY for barrier counters / roster / preds (tiny, cross-L2)
__device__ __forceinline__ float aloadf(const float* p){
  return __hip_atomic_load(p, __ATOMIC_RELAXED, __HIP_MEMORY_SCOPE_AGENT);
}
__device__ __forceinline__ void astoref(float* p, float v){
  __hip_atomic_store(p, v, __ATOMIC_RELAXED, __HIP_MEMORY_SCOPE_AGENT);
}

// async global->LDS, 16B/lane, aux=1 (sc0: bypass L1, read XCD-local L2)
__device__ __forceinline__ void glds16(const u16* g, u16* l){
  __builtin_amdgcn_global_load_lds(
      (const __attribute__((address_space(1))) void*)g,
      (__attribute__((address_space(3))) void*)l, 16, 0, 1);
}

// LDS-only barrier: orders ds ops across waves WITHOUT draining vmcnt —
// keeps primed weight loads in flight through the epilogue (drained at gbar).
__device__ __forceinline__ void bar_lds(){
  asm volatile("s_waitcnt lgkmcnt(0)" ::: "memory");
  __builtin_amdgcn_s_barrier();
}

struct Params {
  const float* xT;     // transposed input [S][B]
  const u16 *We0, *We1i, *We1h, *Wd0, *Wd1i, *Wd1h;
  const float *be0, *be1, *bd0, *bd1, *wxe, *wxd, *fcW, *fcbp;
  u16 *h0buf, *h1buf;
  float* preds;
  unsigned* gcnt;
  unsigned* roster;
  float* out;
};

// ---------------- prep kernels ----------------
// orig row = gate*512 + hu  ->  new row = (hu>>3)*32 + gate*8 + (hu&7)
__global__ void k_reorder_w(const float* __restrict__ src, u16* __restrict__ dst){
  int idx  = blockIdx.x * 256 + threadIdx.x;
  int k    = idx & (HID-1);
  int orig = idx >> 9;
  int gate = orig >> 9, hu = orig & (HID-1);
  int nr   = ((hu >> 3) << 5) + (gate << 3) + (hu & 7);
  dst[(size_t)nr * HID + k] = f2bf(src[idx]);
}

__global__ void k_prep_small(const float* __restrict__ bih, const float* __restrict__ bhh,
                             float* __restrict__ bdst,
                             const float* __restrict__ wcol, float* __restrict__ wdst){
  int orig = blockIdx.x * 256 + threadIdx.x;
  int gate = orig >> 9, hu = orig & (HID-1);
  int nr   = ((hu >> 3) << 5) + (gate << 3) + (hu & 7);
  bdst[nr] = bih[orig] + bhh[orig];
  if (wcol) wdst[nr] = wcol[orig];
}

// x[B][S] -> xT[S][B]: coalesced per-phase x reads, one-time
__global__ void k_xpose(const float* __restrict__ x, float* __restrict__ xT){
  int idx = blockIdx.x * 256 + threadIdx.x;
  int b = idx / S_LEN, s = idx - b*S_LEN;
  xT[(size_t)s * BATCH + b] = x[idx];
}

// ---------------- per-XCD barrier (32 blocks), RELAXED ----------------
// gbar's __syncthreads drains vmcnt(0): h stores are in L2 before tid0 bumps the
// counter -> peers that observe the count observe h. Primed weight loads also
// drain here: their fetch overlapped the preceding epilogue; values stay in VGPRs.
__device__ __forceinline__ void gbar(unsigned* cnt, unsigned& epoch){
  __syncthreads();
  ++epoch;
  if (threadIdx.x == 0){
    __hip_atomic_fetch_add(cnt, 1u, __ATOMIC_RELAXED, __HIP_MEMORY_SCOPE_AGENT);
    const unsigned tgt = epoch * 32u;
    while (__hip_atomic_load(cnt, __ATOMIC_RELAXED, __HIP_MEMORY_SCOPE_AGENT) < tgt)
      __builtin_amdgcn_s_sleep(1);
  }
  __syncthreads();
}

// ---------------- A-tile staging (sc0 -> XCD L2), source-swizzled ----------------
__device__ __forceinline__ void stage_tile(const u16* __restrict__ Ag, u16* lA,
                                           int wave, int lane){
  const int r_in = lane >> 2, qq = lane & 3;
  const int qg = qq ^ ((r_in >> 2) & 3);
  #pragma unroll
  for (int j = 0; j < 8; ++j){
    const int idx = wave*8 + j;
    const int c = idx >> 2, rq = idx & 3;
    const u16* g = Ag + (size_t)(rq*16 + r_in)*HID + c*32 + qg*8;
    glds16(g, lA + c*2048 + rq*512);
  }
}

// K-chunk permutation: cc = (cb + cs*i) & 15, cb = dir?15:0, cs = dir?-1:+1.
// PURE zigzag across phases (R5: FETCH -44%). Split-stream pipelining below
// trades some zigzag residency for fetch/epilogue overlap.

// ---------------- prime helpers: issue B-stream loads into registers ----------
__device__ __forceinline__ void prime8(const u16* __restrict__ B, int4 (&q)[8][2],
                                       const int (&boff)[2], int cb, int cs){
  #pragma unroll
  for (int st = 0; st < 8; ++st){
    const int cc = (cb + cs*st) & 15;
    #pragma unroll
    for (int nf = 0; nf < 2; ++nf)
      q[st][nf] = *(const int4*)(B + boff[nf] + cc*32);
  }
}
__device__ __forceinline__ void prime4(const u16* __restrict__ B, int4 (&q)[4][2],
                                       const int (&boff)[2], int cb, int cs){
  #pragma unroll
  for (int st = 0; st < 4; ++st){
    const int cc = (cb + cs*st) & 15;
    #pragma unroll
    for (int nf = 0; nf < 2; ++nf)
      q[st][nf] = *(const int4*)(B + boff[nf] + cc*32);
  }
}

// ---------------- GEMM: 1 A-tile x 1 B-stream, externally primed depth-8 -------
__device__ __forceinline__ void gemm_1s(
    const u16* lA0, const u16* __restrict__ B0, int4 (&q)[8][2],
    f32x4 (&acc)[4][2], const int (&aloff)[4], const int (&boff)[2],
    int cb, int cs)
{
  #pragma unroll
  for (int i = 0; i < 16; ++i){
    const int cc = (cb + cs*i) & 15;
    bf16x8 a0[4];
    #pragma unroll
    for (int mf = 0; mf < 4; ++mf)
      a0[mf] = *(const bf16x8*)&lA0[cc*2048 + aloff[mf]];
    const int st = i & 7;
    #pragma unroll
    for (int mf = 0; mf < 4; ++mf)
      #pragma unroll
      for (int nf = 0; nf < 2; ++nf)
        acc[mf][nf] = MFMA16(a0[mf], __builtin_bit_cast(bf16x8, q[st][nf]), acc[mf][nf]);
    if (i < 8){
      const int cn = (cb + cs*(i+8)) & 15;
      #pragma unroll
      for (int nf = 0; nf < 2; ++nf)
        q[st][nf] = *(const int4*)(B0 + boff[nf] + cn*32);
    }
  }
}

// ---------------- GEMM: 2 A-tiles x 2 B-streams, externally primed depth-4 -----
__device__ __forceinline__ void gemm_2s(
    const u16* lA0, const u16* lA1,
    const u16* __restrict__ B1, const u16* __restrict__ B2,
    int4 (&q1)[4][2], int4 (&q2)[4][2],
    f32x4 (&acc)[4][2], const int (&aloff)[4], const int (&boff)[2],
    int cb, int cs)
{
  #pragma unroll
  for (int i = 0; i < 16; ++i){
    const int cc = (cb + cs*i) & 15;
    bf16x8 a0[4], a1[4];
    #pragma unroll
    for (int mf = 0; mf < 4; ++mf){
      a0[mf] = *(const bf16x8*)&lA0[cc*2048 + aloff[mf]];
      a1[mf] = *(const bf16x8*)&lA1[cc*2048 + aloff[mf]];
    }
    const int st = i & 3;
    #pragma unroll
    for (int mf = 0; mf < 4; ++mf)
      #pragma unroll
      for (int nf = 0; nf < 2; ++nf){
        acc[mf][nf] = MFMA16(a0[mf], __builtin_bit_cast(bf16x8, q1[st][nf]), acc[mf][nf]);
        acc[mf][nf] = MFMA16(a1[mf], __builtin_bit_cast(bf16x8, q2[st][nf]), acc[mf][nf]);
      }
    if (i < 12){
      const int cn = (cb + cs*(i+4)) & 15;
      #pragma unroll
      for (int nf = 0; nf < 2; ++nf){
        q1[st][nf] = *(const int4*)(B1 + boff[nf] + cn*32);
        q2[st][nf] = *(const int4*)(B2 + boff[nf] + cn*32);
      }
    }
  }
}

// ---------------- LSTM cell epilogue (proven gate mapping) ----------------
template<bool X0, bool PRED>
__device__ __forceinline__ void cell_epi(
    f32x4 (&acc)[4][2], float* cst, const float* bv, const float* wxv,
    const float* xin, u16* scr,
    int wave, int quad, int l15, int m0,
    float fcWv, float* predrow)
{
  const int hilane = l15 >> 3, hu7 = l15 & 7;
  #pragma unroll
  for (int mf = 0; mf < 4; ++mf){
    #pragma unroll
    for (int r = 0; r < 4; ++r){
      const float a0 = acc[mf][0][r], a1 = acc[mf][1][r];
      const float p0 = __shfl_xor(a0, 8), p1 = __shfl_xor(a1, 8);
      float gi = (hilane ? p0 : a0) + bv[0];
      float gf = (hilane ? a0 : p0) + bv[1];
      float gg = (hilane ? p1 : a1) + bv[2];
      float go = (hilane ? a1 : p1) + bv[3];
      if (X0){
        const float xt = xin[mf*4 + r];
        gi += xt*wxv[0]; gf += xt*wxv[1]; gg += xt*wxv[2]; go += xt*wxv[3];
      }
      const float c = sigf(gf)*cst[mf*4+r] + sigf(gi)*tanh_f(gg);
      cst[mf*4+r] = c;
      const float h = sigf(go)*tanh_f(c);
      if (!hilane) scr[(mf*16 + quad*4 + r)*72 + wave*8 + hu7] = f2bf(h);
      if (PRED){
        float v = hilane ? 0.f : h*fcWv;
        v += __shfl_xor(v, 1); v += __shfl_xor(v, 2);
        v += __shfl_xor(v, 4); v += __shfl_xor(v, 8);
        if (l15 == 0) atomicAdd(&predrow[m0 + mf*16 + quad*4 + r], v);
      }
    }
  }
}

// drain scratch (64 rows x 64 cols, pitch 72) -> global h (plain stores -> XCD L2)
// lgkm-only barriers: keeps primed weight loads (vmcnt) in flight.
__device__ __forceinline__ void drain_h(const u16* scr, u16* hdst, int m0, int col0, int tid){
  bar_lds();
  const int row = tid >> 3, q = tid & 7;
  const int4 v = *(const int4*)(scr + row*72 + q*8);
  *(int4*)(hdst + (size_t)(m0+row)*HID + col0 + q*8) = v;
  bar_lds();
}

// ---------------- persistent main kernel ----------------
__global__ __launch_bounds__(THREADS, 1) void lstm_main(Params P){
  const int tid = threadIdx.x;
  const int wave = tid >> 6, lane = tid & 63;
  const int l15 = lane & 15, quad = lane >> 4;
  const int hu7 = l15 & 7;

  __shared__ u16 arena[ARENA_ELEMS];   // 140.3 KB -> 1 block/CU -> 32 blocks/XCD
  __shared__ unsigned sslot;
  u16* lA0 = arena;
  u16* lA1 = arena + ATILE;
  u16* scr = arena + SCROFF;

  // ---- dynamic XCD roster ----
  unsigned xcd;
  asm volatile("s_getreg_b32 %0, hwreg(HW_REG_XCC_ID)" : "=s"(xcd));
  if (tid == 0)
    sslot = __hip_atomic_fetch_add(&P.roster[xcd*32], 1u, __ATOMIC_RELAXED,
                                   __HIP_MEMORY_SCOPE_AGENT);
  __syncthreads();
  const int slot  = (int)(sslot & 31u);
  const int m_sub = slot & 3;
  const int n_sub = slot >> 2;
  const int m0   = (int)xcd*256 + m_sub*64;
  const int col0 = n_sub*64;
  const int hu   = col0 + wave*8 + hu7;

  unsigned* cnt = P.gcnt + xcd*32;

  // fragment offsets: read slot = quad ^ swz(l15) (matches staging source permute)
  const int swz = (l15 >> 2) & 3;
  int aloff[4], boff[2];
  #pragma unroll
  for (int mf = 0; mf < 4; ++mf)
    aloff[mf] = (mf*16 + l15)*32 + ((quad ^ swz) << 3);
  #pragma unroll
  for (int nf = 0; nf < 2; ++nf)
    boff[nf] = (n_sub*256 + wave*32 + nf*16 + l15)*HID + quad*8;

  float c0s[16], c1s[16];
  #pragma unroll
  for (int i = 0; i < 16; ++i){ c0s[i] = 0.f; c1s[i] = 0.f; }

  float be0v[4], be1v[4], bd0v[4], bd1v[4], wxev[4], wxdv[4];
  #pragma unroll
  for (int g = 0; g < 4; ++g){
    const int col = n_sub*256 + wave*32 + g*8 + hu7;
    be0v[g] = P.be0[col]; be1v[g] = P.be1[col];
    bd0v[g] = P.bd0[col]; bd1v[g] = P.bd1[col];
    wxev[g] = P.wxe[col]; wxdv[g] = P.wxd[col];
  }
  const float fcWv = P.fcW[hu];
  const float fcb  = P.fcbp[0];

  const size_t mb = (size_t)m0 * HID;
  u16* h0b[2] = { P.h0buf, P.h0buf + HBUF };
  u16* h1b[2] = { P.h1buf, P.h1buf + HBUF };

  unsigned epoch = 0;
  gbar(cnt, epoch);   // roster settled

  // persistent prime register block (held across gbar; weights are constant)
  int4 q0[8][2];
  prime8(P.We0, q0, boff, 0, 1);   // p=0, dir=0

  // ===== encoder: phase p runs layer0(t=p) and layer1(t=p-1) =====
  for (int p = 0; p <= S_LEN; ++p){
    stage_tile(h0b[p & 1] + mb,     lA0, wave, lane);
    stage_tile(h1b[(p+1) & 1] + mb, lA1, wave, lane);

    const int dir = p & 1;
    const int cb  = dir ? 15 : 0;
    const int cs  = dir ? -1 : 1;

    float xin[16];
    if (p < S_LEN){
      #pragma unroll
      for (int mf = 0; mf < 4; ++mf)
        #pragma unroll
        for (int r = 0; r < 4; ++r)
          xin[mf*4+r] = P.xT[(size_t)p*BATCH + m0 + mf*16 + quad*4 + r];
    }

    f32x4 acc0[4][2];
    #pragma unroll
    for (int i = 0; i < 4; ++i)
      #pragma unroll
      for (int j = 0; j < 2; ++j) acc0[i][j] = f32x4{0.f,0.f,0.f,0.f};

    __syncthreads();   // A-tile staging (glds16) + q0 primes drained
    gemm_1s(lA0, P.We0, q0, acc0, aloff, boff, cb, cs);

    // prime layer-1 streams; their fetch overlaps epilogue0 + drain0
    int4 q1[4][2], q2[4][2];
    prime4(P.We1i, q1, boff, cb, cs);
    prime4(P.We1h, q2, boff, cb, cs);
    __builtin_amdgcn_sched_barrier(0);

    if (p < S_LEN){
      cell_epi<true,false>(acc0, c0s, be0v, wxev, xin, scr, wave, quad, l15, m0, 0.f, nullptr);
      drain_h(scr, h0b[(p+1) & 1], m0, col0, tid);
    }

    f32x4 acc1[4][2];
    #pragma unroll
    for (int i = 0; i < 4; ++i)
      #pragma unroll
      for (int j = 0; j < 2; ++j) acc1[i][j] = f32x4{0.f,0.f,0.f,0.f};

    gemm_2s(lA0, lA1, P.We1i, P.We1h, q1, q2, acc1, aloff, boff, cb, cs);

    // prime next phase's first stream; fetch overlaps epilogue1 + gbar spin,
    // values survive the barrier in VGPRs
    if (p < S_LEN){
      const int nd = (p+1) & 1;
      prime8(P.We0, q0, boff, nd ? 15 : 0, nd ? -1 : 1);
    } else {
      prime8(P.Wd0, q0, boff, 0, 1);   // decoder t=0, dir=0
    }
    __builtin_amdgcn_sched_barrier(0);

    if (p >= 1){
      cell_epi<false,false>(acc1, c1s, be1v, nullptr, nullptr, scr, wave, quad, l15, m0, 0.f, nullptr);
      drain_h(scr, h1b[p & 1], m0, col0, tid);
    }
    gbar(cnt, epoch);
  }

  // ===== decoder: 2 phases per step (pred feedback) =====
  for (int t = 0; t < T_LEN; ++t){
    const int dir = t & 1;
    const int cb  = dir ? 15 : 0;
    const int cs  = dir ? -1 : 1;

    if (t > 0 && n_sub == 0 && tid < 64){
      const float pv = aloadf(&P.preds[((t+1) & 1)*BATCH + m0 + tid]);
      P.out[(size_t)(m0 + tid)*T_LEN + (t-1)] = pv + fcb;
    }
    { // phase A: dec layer0 (q0 primed at previous phase-B tail / encoder tail)
      stage_tile(h0b[t & 1] + mb, lA0, wave, lane);
      float xin[16];
      #pragma unroll
      for (int mf = 0; mf < 4; ++mf)
        #pragma unroll
        for (int r = 0; r < 4; ++r){
          const int b = m0 + mf*16 + quad*4 + r;
          xin[mf*4+r] = (t == 0) ? P.xT[(size_t)(S_LEN-1)*BATCH + b]
                                 : (aloadf(&P.preds[((t+1) & 1)*BATCH + b]) + fcb);
        }
      f32x4 acc0[4][2];
      #pragma unroll
      for (int i = 0; i < 4; ++i)
        #pragma unroll
        for (int j = 0; j < 2; ++j) acc0[i][j] = f32x4{0.f,0.f,0.f,0.f};
      __syncthreads();   // staging + q0 primes drained
      gemm_1s(lA0, P.Wd0, q0, acc0, aloff, boff, cb, cs);

      // prime phase-B streams; fetch overlaps epilogueA + drainA + gbar spin
      int4 q1[4][2], q2[4][2];
      prime4(P.Wd1i, q1, boff, cb, cs);
      prime4(P.Wd1h, q2, boff, cb, cs);
      __builtin_amdgcn_sched_barrier(0);

      cell_epi<true,false>(acc0, c0s, bd0v, wxdv, xin, scr, wave, quad, l15, m0, 0.f, nullptr);
      drain_h(scr, h0b[(t+1) & 1], m0, col0, tid);
      gbar(cnt, epoch);

      // phase B: dec layer1 + pred reduce
      if (n_sub == 0 && tid < 64)
        astoref(&P.preds[((t+1) & 1)*BATCH + m0 + tid], 0.f);
      stage_tile(h0b[(t+1) & 1] + mb, lA0, wave, lane);
      stage_tile(h1b[t & 1] + mb,     lA1, wave, lane);
      f32x4 acc1[4][2];
      #pragma unroll
      for (int i = 0; i < 4; ++i)
        #pragma unroll
        for (int j = 0; j < 2; ++j) acc1[i][j] = f32x4{0.f,0.f,0.f,0.f};
      __syncthreads();   // staging drained (q1/q2 already landed at gbar)
      gemm_2s(lA0, lA1, P.Wd1i, P.Wd1h, q1, q2, acc1, aloff, boff, cb, cs);

      // prime next step's phase-A stream across the barrier
      {
        const int nd = (t+1) & 1;
        prime8(P.Wd0, q0, boff, nd ? 15 : 0, nd ? -1 : 1);
      }
      __builtin_amdgcn_sched_barrier(0);

      cell_epi<false,true>(acc1, c1s, bd1v, nullptr, nullptr, scr, wave, quad, l15, m0,
                           fcWv, P.preds + (t & 1)*BATCH);
      drain_h(scr, h1b[(t+1) & 1], m0, col0, tid);
      gbar(cnt, epoch);
    }
  }
  if (n_sub == 0 && tid < 64){
    const float pv = aloadf(&P.preds[((T_LEN-1) & 1)*BATCH + m0 + tid]);
    P.out[(size_t)(m0 + tid)*T_LEN + (T_LEN-1)] = pv + fcb;
  }
}

// ---------------- host launcher ----------------
extern "C" void kernel_launch(void* const* d_in, const int* in_sizes, int n_in,
                              void* d_out, int out_size, void* d_ws, size_t ws_size,
                              hipStream_t stream){
  const float* x     = (const float*)d_in[0];
  const float* eWih0 = (const float*)d_in[1];
  const float* eWhh0 = (const float*)d_in[2];
  const float* ebih0 = (const float*)d_in[3];
  const float* ebhh0 = (const float*)d_in[4];
  const float* eWih1 = (const float*)d_in[5];
  const float* eWhh1 = (const float*)d_in[6];
  const float* ebih1 = (const float*)d_in[7];
  const float* ebhh1 = (const float*)d_in[8];
  const float* dWih0 = (const float*)d_in[9];
  const float* dWhh0 = (const float*)d_in[10];
  const float* dbih0 = (const float*)d_in[11];
  const float* dbhh0 = (const float*)d_in[12];
  const float* dWih1 = (const float*)d_in[13];
  const float* dWhh1 = (const float*)d_in[14];
  const float* dbih1 = (const float*)d_in[15];
  const float* dbhh1 = (const float*)d_in[16];
  const float* fcW   = (const float*)d_in[17];
  const float* fcb   = (const float*)d_in[18];

  char* ws = (char*)d_ws;
  size_t off = 0;
  auto alloc = [&](size_t bytes)->char*{
    char* p = ws + off; off += (bytes + 255) & ~(size_t)255; return p;
  };
  u16* We0  = (u16*)alloc((size_t)2048*512*2);
  u16* We1i = (u16*)alloc((size_t)2048*512*2);
  u16* We1h = (u16*)alloc((size_t)2048*512*2);
  u16* Wd0  = (u16*)alloc((size_t)2048*512*2);
  u16* Wd1i = (u16*)alloc((size_t)2048*512*2);
  u16* Wd1h = (u16*)alloc((size_t)2048*512*2);
  char* zbase = ws + off;
  u16* h0buf = (u16*)alloc(2*HBUF*2);
  u16* h1buf = (u16*)alloc(2*HBUF*2);
  float* preds = (float*)alloc(2*BATCH*4);
  unsigned* gcnt   = (unsigned*)alloc(8*32*4);
  unsigned* roster = (unsigned*)alloc(8*32*4);
  size_t zbytes = (size_t)((ws + off) - zbase);
  float* be0 = (float*)alloc(2048*4);
  float* be1 = (float*)alloc(2048*4);
  float* bd0 = (float*)alloc(2048*4);
  float* bd1 = (float*)alloc(2048*4);
  float* wxe = (float*)alloc(2048*4);
  float* wxd = (float*)alloc(2048*4);
  float* xT  = (float*)alloc((size_t)BATCH*S_LEN*4);

  (void)hipMemsetAsync(zbase, 0, zbytes, stream);
  dim3 gw((2048*512)/256);
  k_reorder_w<<<gw,256,0,stream>>>(eWhh0, We0);
  k_reorder_w<<<gw,256,0,stream>>>(eWih1, We1i);
  k_reorder_w<<<gw,256,0,stream>>>(eWhh1, We1h);
  k_reorder_w<<<gw,256,0,stream>>>(dWhh0, Wd0);
  k_reorder_w<<<gw,256,0,stream>>>(dWih1, Wd1i);
  k_reorder_w<<<gw,256,0,stream>>>(dWhh1, Wd1h);
  k_prep_small<<<8,256,0,stream>>>(ebih0, ebhh0, be0, eWih0, wxe);
  k_prep_small<<<8,256,0,stream>>>(ebih1, ebhh1, be1, (const float*)nullptr, (float*)nullptr);
  k_prep_small<<<8,256,0,stream>>>(dbih0, dbhh0, bd0, dWih0, wxd);
  k_prep_small<<<8,256,0,stream>>>(dbih1, dbhh1, bd1, (const float*)nullptr, (float*)nullptr);
  k_xpose<<<dim3((BATCH*S_LEN)/256),256,0,stream>>>(x, xT);

  Params P{ xT, We0, We1i, We1h, Wd0, Wd1i, Wd1h,
            be0, be1, bd0, bd1, wxe, wxd, fcW, fcb,
            h0buf, h1buf, preds, gcnt, roster, (float*)d_out };
  lstm_main<<<dim3(NBLK), dim3(THREADS), 0, stream>>>(P);
}